// Round 1
// baseline (75.393 us; speedup 1.0000x reference)
//
#include <hip/hip_runtime.h>
#include <hip/hip_bf16.h>
#include <stdint.h>

#define BN 32
#define CIN 64
#define COUTC 64
#define TT 6
#define VV 512
#define NEG_FILL -1000.0f
#define SLOPE 0.2f

using bf16x8 = __attribute__((ext_vector_type(8))) short;
using f32x4  = __attribute__((ext_vector_type(4))) float;

static __device__ __forceinline__ float bf2f(unsigned short u) {
    union { unsigned int i; float f; } x; x.i = ((unsigned int)u) << 16; return x.f;
}
static __device__ __forceinline__ unsigned short f2bf(float f) {
    union { float f; unsigned int i; } x; x.f = f;
    unsigned int r = x.i + 0x7FFFu + ((x.i >> 16) & 1u);
    return (unsigned short)(r >> 16);
}

#define GLD16(gp, lp) __builtin_amdgcn_global_load_lds( \
    (const __attribute__((address_space(1))) void*)(gp), \
    (__attribute__((address_space(3))) void*)(lp), 16, 0, 0)

// ---------------- k1: xc[n,o,t,v] = sum_i x[n,i,t,v] W[o,i] + b[o]  (bf16 out)
__global__ __launch_bounds__(256) void k1_conv(const float* __restrict__ x,
                                               const float* __restrict__ W,
                                               const float* __restrict__ bias,
                                               unsigned short* __restrict__ xcb) {
    __shared__ float xs[CIN][256];
    __shared__ float wt[CIN][68];   // transposed W, padded (16B-aligned rows, conflict-tamed)
    int bid = blockIdx.x;           // (n*T + t)*2 + vt
    int vt = bid & 1; int nt = bid >> 1; int t = nt % TT; int n = nt / TT;
    int tid = threadIdx.x;
    int v0 = vt * 256;

    // stage W transposed: read coalesced over i
    for (int k = 0; k < 16; ++k) {
        int e = k * 256 + tid; int o = e >> 6, i = e & 63;
        wt[i][o] = W[o * CIN + i];
    }
    // stage x tile [64][256] f32
    const float* xg = x + ((size_t)n * CIN * TT + t) * VV + v0;
    for (int k = 0; k < 16; ++k) {
        int idx = k * 256 + tid;        // float4 granule: 64 per row
        int i = idx >> 6; int c4 = idx & 63;
        *(f32x4*)&xs[i][c4 * 4] = *(const f32x4*)&xg[(size_t)i * TT * VV + c4 * 4];
    }
    __syncthreads();

    int og = tid >> 5;   // 0..7  -> o = og*8 + a
    int vg = tid & 31;   // 0..31 -> v = vg*4+{0..3} and 128+vg*4+{0..3}
    float acc[8][8];
    #pragma unroll
    for (int a = 0; a < 8; ++a)
        #pragma unroll
        for (int c = 0; c < 8; ++c) acc[a][c] = 0.f;

    #pragma unroll 4
    for (int i = 0; i < CIN; ++i) {
        f32x4 xa = *(const f32x4*)&xs[i][vg * 4];
        f32x4 xb = *(const f32x4*)&xs[i][128 + vg * 4];
        f32x4 wa = *(const f32x4*)&wt[i][og * 8];
        f32x4 wb = *(const f32x4*)&wt[i][og * 8 + 4];
        #pragma unroll
        for (int a = 0; a < 8; ++a) {
            float wv = (a < 4) ? wa[a] : wb[a - 4];
            #pragma unroll
            for (int c = 0; c < 8; ++c) {
                float xv = (c < 4) ? xa[c] : xb[c - 4];
                acc[a][c] += wv * xv;
            }
        }
    }

    size_t outbase = ((size_t)(n * COUTC) * TT + t) * VV;
    #pragma unroll
    for (int a = 0; a < 8; ++a) {
        int o = og * 8 + a;
        float bv = bias[o];
        ushort4 p0, p1;
        p0.x = f2bf(acc[a][0] + bv); p0.y = f2bf(acc[a][1] + bv);
        p0.z = f2bf(acc[a][2] + bv); p0.w = f2bf(acc[a][3] + bv);
        p1.x = f2bf(acc[a][4] + bv); p1.y = f2bf(acc[a][5] + bv);
        p1.z = f2bf(acc[a][6] + bv); p1.w = f2bf(acc[a][7] + bv);
        size_t off = outbase + (size_t)o * TT * VV + v0 + vg * 4;
        *(ushort4*)&xcb[off]       = p0;
        *(ushort4*)&xcb[off + 128] = p1;
    }
}

// ---------------- k1b: s_i[n,v], s_j[n,v]
__global__ __launch_bounds__(256) void k1b_scores(const unsigned short* __restrict__ xcb,
                                                  const float* __restrict__ l1w,
                                                  const float* __restrict__ l2w,
                                                  const float* __restrict__ l2b_,
                                                  float* __restrict__ si,
                                                  float* __restrict__ sj) {
    int g = blockIdx.x * 256 + threadIdx.x;   // 0..16383
    int n = g >> 9, v = g & 511;
    float l2wr[TT];
    #pragma unroll
    for (int t = 0; t < TT; ++t) l2wr[t] = l2w[t];
    float aS = 0.f, aD = 0.f, sws = 0.f, swd = 0.f;
    const unsigned short* p = xcb + (size_t)n * COUTC * TT * VV + v;
    #pragma unroll 4
    for (int c = 0; c < COUTC; ++c) {
        float wS = l1w[c], wD = l1w[COUTC + c];
        sws += wS; swd += wD;
        float dot = 0.f;
        #pragma unroll
        for (int t = 0; t < TT; ++t) dot += bf2f(p[((size_t)c * TT + t) * VV]) * l2wr[t];
        aS += dot * wS; aD += dot * wD;
    }
    float l2b = l2b_[0];
    si[g] = aS + l2b * sws;
    sj[g] = aD + l2b * swd;
}

// ---------------- k2: per-row softmax -> a4 (f32, to d_out)
__global__ __launch_bounds__(256) void k2_softmax(const float* __restrict__ A,
                                                  const float* __restrict__ si,
                                                  const float* __restrict__ sj,
                                                  const float* __restrict__ l1b_,
                                                  float* __restrict__ a4out) {
    int row = blockIdx.x * 4 + (threadIdx.x >> 6);   // (n,i) row, wave per row
    int lane = threadIdx.x & 63;
    int n = row >> 9, i = row & 511;
    float l1b = l1b_[0];
    float s_i = si[row];
    const float* mrow = A + ((size_t)n * 8 + 7) * VV * VV + (size_t)i * VV;
    const float* sjn  = sj + n * VV;

    f32x4 m0  = *(const f32x4*)&mrow[lane * 8];
    f32x4 m1  = *(const f32x4*)&mrow[lane * 8 + 4];
    f32x4 sj0 = *(const f32x4*)&sjn[lane * 8];
    f32x4 sj1 = *(const f32x4*)&sjn[lane * 8 + 4];

    float sc[8];
    float mx = -1e30f;
    #pragma unroll
    for (int e = 0; e < 8; ++e) {
        float mk = (e < 4) ? m0[e] : m1[e - 4];
        float s  = s_i + ((e < 4) ? sj0[e] : sj1[e - 4]) + l1b;
        s = (s >= 0.f) ? s : SLOPE * s;          // leaky_relu
        s = (mk == 0.f) ? NEG_FILL : s;          // mask fill
        sc[e] = s;
        mx = fmaxf(mx, s);
    }
    #pragma unroll
    for (int off = 32; off; off >>= 1) mx = fmaxf(mx, __shfl_xor(mx, off));
    float sum = 0.f;
    #pragma unroll
    for (int e = 0; e < 8; ++e) { sc[e] = __expf(sc[e] - mx); sum += sc[e]; }
    #pragma unroll
    for (int off = 32; off; off >>= 1) sum += __shfl_xor(sum, off);
    float inv = 1.f / sum;
    f32x4 o0, o1;
    #pragma unroll
    for (int e = 0; e < 4; ++e) { o0[e] = sc[e] * inv; o1[e] = sc[e + 4] * inv; }
    *(f32x4*)&a4out[(size_t)row * VV + lane * 8]     = o0;
    *(f32x4*)&a4out[(size_t)row * VV + lane * 8 + 4] = o1;
}

// ---------------- k2b: a4T[n,w,v] = bf16(a4[n,v,w])
__global__ __launch_bounds__(256) void k2b_transpose(const float* __restrict__ a4f,
                                                     unsigned short* __restrict__ a4t) {
    __shared__ float tile[64][65];
    int bid = blockIdx.x;                 // n*64 + wt*8 + vt
    int n = bid >> 6; int r = bid & 63; int wt_ = r >> 3, vt = r & 7;
    int w0 = wt_ * 64, v0 = vt * 64;
    int ty = threadIdx.x >> 6, tx = threadIdx.x & 63;
    const float* src = a4f + (size_t)n * VV * VV;
    #pragma unroll
    for (int k = 0; k < 16; ++k) {
        int row = k * 4 + ty;
        tile[row][tx] = src[(size_t)(v0 + row) * VV + w0 + tx];
    }
    __syncthreads();
    unsigned short* dst = a4t + (size_t)n * VV * VV;
    #pragma unroll
    for (int k = 0; k < 16; ++k) {
        int row = k * 4 + ty;
        dst[(size_t)(w0 + row) * VV + v0 + tx] = f2bf(tile[tx][row]);
    }
}

// ---------------- k3: out[n,r,w] = sum_v xc_bf[n,r,v] * a4T[n,w,v]   (MFMA bf16)
__global__ __launch_bounds__(256) void k3_gemm(const unsigned short* __restrict__ xcb,
                                               const unsigned short* __restrict__ a4t,
                                               float* __restrict__ outp) {
    __shared__ unsigned short As[128 * 32];   // [row r][k] rows of 32 bf16 (64B)
    __shared__ unsigned short Bs[128 * 32];   // [row w][k]
    int bid = blockIdx.x;                 // n*12 + rt*4 + wt
    int n = bid / 12; int s = bid % 12; int rt = s >> 2, wt_ = s & 3;
    int r0 = rt * 128, w0 = wt_ * 128;
    int tid = threadIdx.x; int wv = tid >> 6, ln = tid & 63;
    int wr = wv >> 1, wc = wv & 1;
    const unsigned short* Ag = xcb + (size_t)n * (COUTC * TT) * VV;
    const unsigned short* Bg = a4t + (size_t)n * VV * VV;

    f32x4 acc[4][4] = {};
    int lrow = ln >> 2;
    int lcol = (ln & 3) * 8;
    int fr   = ln & 15;          // frag M/N index
    int fk   = (ln >> 4) * 8;    // frag k-octet

    for (int kt = 0; kt < 16; ++kt) {
        int k0 = kt * 32;
        #pragma unroll
        for (int c2 = 0; c2 < 2; ++c2) {
            int rowbase = wv * 32 + c2 * 16;
            int row = rowbase + lrow;
            GLD16(Ag + (size_t)(r0 + row) * VV + k0 + lcol, &As[rowbase * 32]);
            GLD16(Bg + (size_t)(w0 + row) * VV + k0 + lcol, &Bs[rowbase * 32]);
        }
        __syncthreads();
        bf16x8 af[4], bfv[4];
        #pragma unroll
        for (int mi = 0; mi < 4; ++mi)
            af[mi] = *(const bf16x8*)&As[(wr * 64 + mi * 16 + fr) * 32 + fk];
        #pragma unroll
        for (int ni = 0; ni < 4; ++ni)
            bfv[ni] = *(const bf16x8*)&Bs[(wc * 64 + ni * 16 + fr) * 32 + fk];
        #pragma unroll
        for (int mi = 0; mi < 4; ++mi)
            #pragma unroll
            for (int ni = 0; ni < 4; ++ni)
                acc[mi][ni] = __builtin_amdgcn_mfma_f32_16x16x32_bf16(af[mi], bfv[ni], acc[mi][ni], 0, 0, 0);
        __syncthreads();
    }

    float* og = outp + (size_t)n * (COUTC * TT) * VV;
    #pragma unroll
    for (int mi = 0; mi < 4; ++mi) {
        int rbase = r0 + wr * 64 + mi * 16 + (ln >> 4) * 4;
        #pragma unroll
        for (int ni = 0; ni < 4; ++ni) {
            int col = w0 + wc * 64 + ni * 16 + (ln & 15);
            #pragma unroll
            for (int q = 0; q < 4; ++q)
                og[(size_t)(rbase + q) * VV + col] = acc[mi][ni][q];
        }
    }
}

extern "C" void kernel_launch(void* const* d_in, const int* in_sizes, int n_in,
                              void* d_out, int out_size, void* d_ws, size_t ws_size,
                              hipStream_t stream) {
    const float* x      = (const float*)d_in[0];
    const float* A      = (const float*)d_in[1];
    const float* conv_w = (const float*)d_in[2];
    const float* conv_b = (const float*)d_in[3];
    const float* l1w    = (const float*)d_in[4];
    const float* l1b    = (const float*)d_in[5];
    const float* l2w    = (const float*)d_in[6];
    const float* l2b    = (const float*)d_in[7];

    float* outp  = (float*)d_out;                          // (N,COUT,T,V)
    float* a4out = outp + (size_t)BN * COUTC * TT * VV;    // (N,1,V,V)

    unsigned short* xcb = (unsigned short*)d_ws;                         // 12.6 MB bf16 xc
    unsigned short* a4t = xcb + (size_t)BN * COUTC * TT * VV;            // 16.8 MB bf16 a4T
    float* si = (float*)(a4t + (size_t)BN * VV * VV);
    float* sj = si + BN * VV;

    k1_conv     <<<BN * TT * 2, 256, 0, stream>>>(x, conv_w, conv_b, xcb);
    k1b_scores  <<<BN * VV / 256, 256, 0, stream>>>(xcb, l1w, l2w, l2b, si, sj);
    k2_softmax  <<<BN * VV / 4, 256, 0, stream>>>(A, si, sj, l1b, a4out);
    k2b_transpose<<<BN * 64, 256, 0, stream>>>(a4out, a4t);
    k3_gemm     <<<BN * 12, 256, 0, stream>>>(xcb, a4t, outp);
}

// Round 4
// 68.192 us; speedup vs baseline: 1.1056x; 1.1056x over previous
//
#include <hip/hip_runtime.h>
#include <hip/hip_bf16.h>
#include <stdint.h>

#define BN 32
#define CIN 64
#define COUTC 64
#define TT 6
#define VV 512
#define NEG_FILL -1000.0f
#define SLOPE 0.2f

using bf16x8 = __attribute__((ext_vector_type(8))) short;
using f32x4  = __attribute__((ext_vector_type(4))) float;

static __device__ __forceinline__ float bf2f(unsigned short u) {
    union { unsigned int i; float f; } x; x.i = ((unsigned int)u) << 16; return x.f;
}
static __device__ __forceinline__ unsigned short f2bf(float f) {
    union { float f; unsigned int i; } x; x.f = f;
    unsigned int r = x.i + 0x7FFFu + ((x.i >> 16) & 1u);
    return (unsigned short)(r >> 16);
}

#define GLD16(gp, lp) __builtin_amdgcn_global_load_lds( \
    (const __attribute__((address_space(1))) void*)(gp), \
    (__attribute__((address_space(3))) void*)(lp), 16, 0, 0)

// ---------------- k1: xc[n,o,t,v] = sum_i x[n,i,t,v] W[o,i] + b[o]  (bf16 out)
// (unchanged from round 1 — proven)
__global__ __launch_bounds__(256) void k1_conv(const float* __restrict__ x,
                                               const float* __restrict__ W,
                                               const float* __restrict__ bias,
                                               unsigned short* __restrict__ xcb) {
    __shared__ float xs[CIN][256];
    __shared__ float wt[CIN][68];
    int bid = blockIdx.x;           // (n*T + t)*2 + vt
    int vt = bid & 1; int nt = bid >> 1; int t = nt % TT; int n = nt / TT;
    int tid = threadIdx.x;
    int v0 = vt * 256;

    for (int k = 0; k < 16; ++k) {
        int e = k * 256 + tid; int o = e >> 6, i = e & 63;
        wt[i][o] = W[o * CIN + i];
    }
    const float* xg = x + ((size_t)n * CIN * TT + t) * VV + v0;
    for (int k = 0; k < 16; ++k) {
        int idx = k * 256 + tid;
        int i = idx >> 6; int c4 = idx & 63;
        *(f32x4*)&xs[i][c4 * 4] = *(const f32x4*)&xg[(size_t)i * TT * VV + c4 * 4];
    }
    __syncthreads();

    int og = tid >> 5;
    int vg = tid & 31;
    float acc[8][8];
    #pragma unroll
    for (int a = 0; a < 8; ++a)
        #pragma unroll
        for (int c = 0; c < 8; ++c) acc[a][c] = 0.f;

    #pragma unroll 4
    for (int i = 0; i < CIN; ++i) {
        f32x4 xa = *(const f32x4*)&xs[i][vg * 4];
        f32x4 xb = *(const f32x4*)&xs[i][128 + vg * 4];
        f32x4 wa = *(const f32x4*)&wt[i][og * 8];
        f32x4 wb = *(const f32x4*)&wt[i][og * 8 + 4];
        #pragma unroll
        for (int a = 0; a < 8; ++a) {
            float wv = (a < 4) ? wa[a] : wb[a - 4];
            #pragma unroll
            for (int c = 0; c < 8; ++c) {
                float xv = (c < 4) ? xa[c] : xb[c - 4];
                acc[a][c] += wv * xv;
            }
        }
    }

    size_t outbase = ((size_t)(n * COUTC) * TT + t) * VV;
    #pragma unroll
    for (int a = 0; a < 8; ++a) {
        int o = og * 8 + a;
        float bv = bias[o];
        ushort4 p0, p1;
        p0.x = f2bf(acc[a][0] + bv); p0.y = f2bf(acc[a][1] + bv);
        p0.z = f2bf(acc[a][2] + bv); p0.w = f2bf(acc[a][3] + bv);
        p1.x = f2bf(acc[a][4] + bv); p1.y = f2bf(acc[a][5] + bv);
        p1.z = f2bf(acc[a][6] + bv); p1.w = f2bf(acc[a][7] + bv);
        size_t off = outbase + (size_t)o * TT * VV + v0 + vg * 4;
        *(ushort4*)&xcb[off]       = p0;
        *(ushort4*)&xcb[off + 128] = p1;
    }
}

// ---------------- k1b: s_i[n,v], s_j[n,v]  (unchanged — proven)
__global__ __launch_bounds__(256) void k1b_scores(const unsigned short* __restrict__ xcb,
                                                  const float* __restrict__ l1w,
                                                  const float* __restrict__ l2w,
                                                  const float* __restrict__ l2b_,
                                                  float* __restrict__ si,
                                                  float* __restrict__ sj) {
    int g = blockIdx.x * 256 + threadIdx.x;
    int n = g >> 9, v = g & 511;
    float l2wr[TT];
    #pragma unroll
    for (int t = 0; t < TT; ++t) l2wr[t] = l2w[t];
    float aS = 0.f, aD = 0.f, sws = 0.f, swd = 0.f;
    const unsigned short* p = xcb + (size_t)n * COUTC * TT * VV + v;
    #pragma unroll 4
    for (int c = 0; c < COUTC; ++c) {
        float wS = l1w[c], wD = l1w[COUTC + c];
        sws += wS; swd += wD;
        float dot = 0.f;
        #pragma unroll
        for (int t = 0; t < TT; ++t) dot += bf2f(p[((size_t)c * TT + t) * VV]) * l2wr[t];
        aS += dot * wS; aD += dot * wD;
    }
    float l2b = l2b_[0];
    si[g] = aS + l2b * sws;
    sj[g] = aD + l2b * swd;
}

// ---------------- k2: softmax rows -> a4 f32 (d_out) + fused LDS transpose
//                  -> a4t[n][w][i] bf16 (ws). Replaces old k2 + k2b.
__global__ __launch_bounds__(256) void k2_softmax(const float* __restrict__ A,
                                                  const float* __restrict__ si,
                                                  const float* __restrict__ sj,
                                                  const float* __restrict__ l1b_,
                                                  float* __restrict__ a4out,
                                                  unsigned short* __restrict__ a4t) {
    __shared__ unsigned short tile[32][520];   // 32 rows x 512 (+8 pad), 32.5 KB
    int blk = blockIdx.x;                 // n*16 + ib
    int n = blk >> 4; int i0 = (blk & 15) * 32;
    int wv = threadIdx.x >> 6, lane = threadIdx.x & 63;
    float l1b = l1b_[0];
    const float* sjn = sj + n * VV;
    f32x4 sj0 = *(const f32x4*)&sjn[lane * 8];       // hoisted: same for all rows of n
    f32x4 sj1 = *(const f32x4*)&sjn[lane * 8 + 4];

    for (int it = 0; it < 8; ++it) {
        int il = it * 4 + wv;             // local row 0..31
        int i  = i0 + il;
        int row = n * VV + i;
        float s_i = si[row];
        const float* mrow = A + ((size_t)n * 8 + 7) * VV * VV + (size_t)i * VV;
        f32x4 m0 = *(const f32x4*)&mrow[lane * 8];
        f32x4 m1 = *(const f32x4*)&mrow[lane * 8 + 4];

        float sc[8];
        float mx = -1e30f;
        #pragma unroll
        for (int e = 0; e < 8; ++e) {
            float mk = (e < 4) ? m0[e] : m1[e - 4];
            float s  = s_i + ((e < 4) ? sj0[e] : sj1[e - 4]) + l1b;
            s = (s >= 0.f) ? s : SLOPE * s;
            s = (mk == 0.f) ? NEG_FILL : s;
            sc[e] = s;
            mx = fmaxf(mx, s);
        }
        #pragma unroll
        for (int off = 32; off; off >>= 1) mx = fmaxf(mx, __shfl_xor(mx, off));
        float sum = 0.f;
        #pragma unroll
        for (int e = 0; e < 8; ++e) { sc[e] = __expf(sc[e] - mx); sum += sc[e]; }
        #pragma unroll
        for (int off = 32; off; off >>= 1) sum += __shfl_xor(sum, off);
        float inv = 1.f / sum;
        f32x4 o0, o1;
        bf16x8 pk;
        #pragma unroll
        for (int e = 0; e < 4; ++e) {
            o0[e] = sc[e] * inv; o1[e] = sc[e + 4] * inv;
            pk[e]     = (short)f2bf(o0[e]);
            pk[e + 4] = (short)f2bf(o1[e]);
        }
        *(f32x4*)&a4out[(size_t)row * VV + lane * 8]     = o0;
        *(f32x4*)&a4out[(size_t)row * VV + lane * 8 + 4] = o1;
        *(bf16x8*)&tile[il][lane * 8] = pk;          // 16B-aligned (row stride 1040B)
    }
    __syncthreads();

    // transposed write-out: a4t[n][w][i0..i0+31]
    int i4    = (threadIdx.x & 7) * 4;
    int wbase = threadIdx.x >> 3;         // 0..31
    unsigned short* dst = a4t + (size_t)n * VV * VV + i0;
    #pragma unroll
    for (int ws = 0; ws < 16; ++ws) {
        int w = ws * 32 + wbase;
        ushort4 val;
        val.x = tile[i4 + 0][w];
        val.y = tile[i4 + 1][w];
        val.z = tile[i4 + 2][w];
        val.w = tile[i4 + 3][w];
        *(ushort4*)&dst[(size_t)w * VV + i4] = val;
    }
}

// ---------------- k3: out[n,r,w] = sum_v xc[n,r,v] * a4t[n,w,v]   (MFMA bf16)
// Round-1 fragment math; both operands staged [row][32] with quarter-XOR
// swizzle (LDS[r][q] = G[r][q^s(r)], s(r)=(r>>1)&3; read q = fkq^s(r)).
// Double-buffered: STAGE(next) issued before compute, one barrier per K-step.
__global__ __launch_bounds__(256) void k3_gemm(const unsigned short* __restrict__ xcb,
                                               const unsigned short* __restrict__ a4t,
                                               float* __restrict__ outp) {
    __shared__ __align__(16) unsigned short As[2][128 * 32];   // 2 x 8 KB
    __shared__ __align__(16) unsigned short Bs[2][128 * 32];   // 2 x 8 KB

    int bid = blockIdx.x;                 // n*12 + rt*4 + wt
    int n = bid / 12; int s = bid % 12; int rt = s >> 2, wt_ = s & 3;
    int r0 = rt * 128, w0 = wt_ * 128;
    int tid = threadIdx.x; int wv = tid >> 6, ln = tid & 63;
    int wr = wv >> 1, wc = wv & 1;
    const unsigned short* Ag = xcb + (size_t)n * (COUTC * TT) * VV;
    const unsigned short* Bg = a4t + (size_t)n * VV * VV;

    int fr  = ln & 15;
    int fkq = ln >> 4;
    int a_rl = ln >> 2;        // row within 16-row staging call
    int a_q  = ln & 3;         // 8-elem quarter slot

    f32x4 acc[4][4] = {};

#define STAGE(bsel, kt) do {                                                           \
        int k0_ = (kt) * 32;                                                           \
        _Pragma("unroll")                                                              \
        for (int c2 = 0; c2 < 2; ++c2) {                                               \
            int rowbase = wv * 32 + c2 * 16;                                           \
            int row_l = rowbase + a_rl;                                                \
            int sw = ((a_q ^ ((row_l >> 1) & 3)) << 3);                                \
            GLD16(Ag + (size_t)(r0 + row_l) * VV + k0_ + sw, &As[bsel][rowbase * 32]); \
            GLD16(Bg + (size_t)(w0 + row_l) * VV + k0_ + sw, &Bs[bsel][rowbase * 32]); \
        }                                                                              \
    } while (0)

    STAGE(0, 0);
    __syncthreads();

    for (int kt = 0; kt < 16; ++kt) {
        int cur = kt & 1;
        if (kt < 15) STAGE(cur ^ 1, kt + 1);   // prefetch next K-tile into other buffer

        bf16x8 af[4], bfv[4];
        #pragma unroll
        for (int mi = 0; mi < 4; ++mi) {
            int r = wr * 64 + mi * 16 + fr;
            af[mi] = *(const bf16x8*)&As[cur][r * 32 + ((fkq ^ ((r >> 1) & 3)) << 3)];
        }
        #pragma unroll
        for (int ni = 0; ni < 4; ++ni) {
            int w = wc * 64 + ni * 16 + fr;
            bfv[ni] = *(const bf16x8*)&Bs[cur][w * 32 + ((fkq ^ ((w >> 1) & 3)) << 3)];
        }
        #pragma unroll
        for (int ni = 0; ni < 4; ++ni)
            #pragma unroll
            for (int mi = 0; mi < 4; ++mi)
                acc[mi][ni] = __builtin_amdgcn_mfma_f32_16x16x32_bf16(af[mi], bfv[ni], acc[mi][ni], 0, 0, 0);

        __syncthreads();   // drains vmcnt (prefetch done) + lgkmcnt; guards buffer swap
    }
#undef STAGE

    float* og = outp + (size_t)n * (COUTC * TT) * VV;
    #pragma unroll
    for (int mi = 0; mi < 4; ++mi) {
        int rbase = r0 + wr * 64 + mi * 16 + (ln >> 4) * 4;
        #pragma unroll
        for (int ni = 0; ni < 4; ++ni) {
            int col = w0 + wc * 64 + ni * 16 + (ln & 15);
            #pragma unroll
            for (int q = 0; q < 4; ++q)
                og[(size_t)(rbase + q) * VV + col] = acc[mi][ni][q];
        }
    }
}

extern "C" void kernel_launch(void* const* d_in, const int* in_sizes, int n_in,
                              void* d_out, int out_size, void* d_ws, size_t ws_size,
                              hipStream_t stream) {
    const float* x      = (const float*)d_in[0];
    const float* A      = (const float*)d_in[1];
    const float* conv_w = (const float*)d_in[2];
    const float* conv_b = (const float*)d_in[3];
    const float* l1w    = (const float*)d_in[4];
    const float* l1b    = (const float*)d_in[5];
    const float* l2w    = (const float*)d_in[6];
    const float* l2b    = (const float*)d_in[7];

    float* outp  = (float*)d_out;                          // (N,COUT,T,V)
    float* a4out = outp + (size_t)BN * COUTC * TT * VV;    // (N,1,V,V)

    unsigned short* xcb = (unsigned short*)d_ws;                         // bf16 xc
    unsigned short* a4t = xcb + (size_t)BN * COUTC * TT * VV;            // bf16 a4^T [n][w][i]
    float* si = (float*)(a4t + (size_t)BN * VV * VV);
    float* sj = si + BN * VV;

    k1_conv    <<<BN * TT * 2, 256, 0, stream>>>(x, conv_w, conv_b, xcb);
    k1b_scores <<<BN * VV / 256, 256, 0, stream>>>(xcb, l1w, l2w, l2b, si, sj);
    k2_softmax <<<BN * 16, 256, 0, stream>>>(A, si, sj, l1b, a4out, a4t);
    k3_gemm    <<<BN * 12, 256, 0, stream>>>(xcb, a4t, outp);
}

// Round 5
// 65.671 us; speedup vs baseline: 1.1480x; 1.0384x over previous
//
#include <hip/hip_runtime.h>
#include <hip/hip_bf16.h>
#include <stdint.h>

#define BN 32
#define CIN 64
#define COUTC 64
#define TT 6
#define VV 512
#define NEG_FILL -1000.0f
#define SLOPE 0.2f

using bf16x8 = __attribute__((ext_vector_type(8))) short;
using f32x4  = __attribute__((ext_vector_type(4))) float;

static __device__ __forceinline__ float bf2f(unsigned short u) {
    union { unsigned int i; float f; } x; x.i = ((unsigned int)u) << 16; return x.f;
}
static __device__ __forceinline__ unsigned short f2bf(float f) {
    union { float f; unsigned int i; } x; x.f = f;
    unsigned int r = x.i + 0x7FFFu + ((x.i >> 16) & 1u);
    return (unsigned short)(r >> 16);
}

#define GLD16(gp, lp) __builtin_amdgcn_global_load_lds( \
    (const __attribute__((address_space(1))) void*)(gp), \
    (__attribute__((address_space(3))) void*)(lp), 16, 0, 0)

// ---------------- k0: si/sj = l2b * sum(w_src/dst)  (constant init)
__global__ __launch_bounds__(256) void k0_init(const float* __restrict__ l1w,
                                               const float* __restrict__ l2b_,
                                               float* __restrict__ si) {   // sj = si + BN*VV
    int g = blockIdx.x * 256 + threadIdx.x;       // 0..32767
    float sws = 0.f, swd = 0.f;
    for (int c = 0; c < COUTC; ++c) { sws += l1w[c]; swd += l1w[COUTC + c]; }
    float l2b = l2b_[0];
    si[g] = (g < BN * VV) ? l2b * sws : l2b * swd;
}

// ---------------- k1: xc[n,o,t,v] = sum_i x[n,i,t,v] W[o,i] + b[o]  (bf16 out)
//   + fused si/sj partial: atomicAdd(si[n,v], l2w[t]*sum_o w_src[o]*z[o,v])
//   v-tile = 128 (49 KB LDS -> 3 blocks/CU, grid 768)
__global__ __launch_bounds__(256) void k1_conv(const float* __restrict__ x,
                                               const float* __restrict__ W,
                                               const float* __restrict__ bias,
                                               const float* __restrict__ l1w,
                                               const float* __restrict__ l2w,
                                               unsigned short* __restrict__ xcb,
                                               float* __restrict__ si,
                                               float* __restrict__ sj) {
    __shared__ float xs[CIN][128];
    __shared__ float wt[CIN][68];
    __shared__ float sred[2][128];
    int bid = blockIdx.x;           // (n*T + t)*4 + vq
    int vq = bid & 3; int nt = bid >> 2; int t = nt % TT; int n = nt / TT;
    int tid = threadIdx.x;
    int v0 = vq * 128;

    for (int k = 0; k < 16; ++k) {
        int e = k * 256 + tid; int o = e >> 6, i = e & 63;
        wt[i][o] = W[o * CIN + i];
    }
    const float* xg = x + ((size_t)n * CIN * TT + t) * VV + v0;
    for (int k = 0; k < 8; ++k) {
        int idx = k * 256 + tid;        // f32x4 granule: 32 per row
        int i = idx >> 5; int c4 = idx & 31;
        *(f32x4*)&xs[i][c4 * 4] = *(const f32x4*)&xg[(size_t)i * TT * VV + c4 * 4];
    }
    if (tid < 128) { sred[0][tid] = 0.f; sred[1][tid] = 0.f; }
    __syncthreads();

    int og = tid >> 5;   // 0..7  -> o = og*8 + a
    int vg = tid & 31;   // 0..31 -> v = vg*4+{0..3}
    float acc[8][4];
    #pragma unroll
    for (int a = 0; a < 8; ++a)
        #pragma unroll
        for (int c = 0; c < 4; ++c) acc[a][c] = 0.f;

    #pragma unroll 4
    for (int i = 0; i < CIN; ++i) {
        f32x4 xa = *(const f32x4*)&xs[i][vg * 4];
        f32x4 wa = *(const f32x4*)&wt[i][og * 8];
        f32x4 wb = *(const f32x4*)&wt[i][og * 8 + 4];
        #pragma unroll
        for (int a = 0; a < 8; ++a) {
            float wv = (a < 4) ? wa[a] : wb[a - 4];
            #pragma unroll
            for (int c = 0; c < 4; ++c) acc[a][c] += wv * xa[c];
        }
    }

    // z = acc + bias; store bf16; fold si/sj partials from f32 z
    float l2wt = l2w[t];
    float pS[4] = {0.f, 0.f, 0.f, 0.f}, pD[4] = {0.f, 0.f, 0.f, 0.f};
    size_t outbase = ((size_t)(n * COUTC) * TT + t) * VV;
    #pragma unroll
    for (int a = 0; a < 8; ++a) {
        int o = og * 8 + a;
        float bv = bias[o];
        float wS = l1w[o], wD = l1w[COUTC + o];
        ushort4 p0;
        float z0 = acc[a][0] + bv, z1 = acc[a][1] + bv;
        float z2 = acc[a][2] + bv, z3 = acc[a][3] + bv;
        pS[0] += wS * z0; pS[1] += wS * z1; pS[2] += wS * z2; pS[3] += wS * z3;
        pD[0] += wD * z0; pD[1] += wD * z1; pD[2] += wD * z2; pD[3] += wD * z3;
        p0.x = f2bf(z0); p0.y = f2bf(z1); p0.z = f2bf(z2); p0.w = f2bf(z3);
        *(ushort4*)&xcb[outbase + (size_t)o * TT * VV + v0 + vg * 4] = p0;
    }
    #pragma unroll
    for (int c = 0; c < 4; ++c) {
        atomicAdd(&sred[0][vg * 4 + c], l2wt * pS[c]);
        atomicAdd(&sred[1][vg * 4 + c], l2wt * pD[c]);
    }
    __syncthreads();
    if (tid < 128)       atomicAdd(&si[n * VV + v0 + tid],       sred[0][tid]);
    else if (tid < 256)  atomicAdd(&sj[n * VV + v0 + tid - 128], sred[1][tid - 128]);
}

// ---------------- k2: softmax rows -> a4 f32 (d_out) + fused LDS transpose
//                  -> a4t[n][w][i] bf16 (ws)
__global__ __launch_bounds__(256) void k2_softmax(const float* __restrict__ A,
                                                  const float* __restrict__ si,
                                                  const float* __restrict__ sj,
                                                  const float* __restrict__ l1b_,
                                                  float* __restrict__ a4out,
                                                  unsigned short* __restrict__ a4t) {
    __shared__ unsigned short tile[32][520];   // 32 rows x 512 (+8 pad), 32.5 KB
    int blk = blockIdx.x;                 // n*16 + ib
    int n = blk >> 4; int i0 = (blk & 15) * 32;
    int wv = threadIdx.x >> 6, lane = threadIdx.x & 63;
    float l1b = l1b_[0];
    const float* sjn = sj + n * VV;
    f32x4 sj0 = *(const f32x4*)&sjn[lane * 8];
    f32x4 sj1 = *(const f32x4*)&sjn[lane * 8 + 4];

    for (int it = 0; it < 8; ++it) {
        int il = it * 4 + wv;             // local row 0..31
        int i  = i0 + il;
        int row = n * VV + i;
        float s_i = si[row];
        const float* mrow = A + ((size_t)n * 8 + 7) * VV * VV + (size_t)i * VV;
        f32x4 m0 = *(const f32x4*)&mrow[lane * 8];
        f32x4 m1 = *(const f32x4*)&mrow[lane * 8 + 4];

        float sc[8];
        float mx = -1e30f;
        #pragma unroll
        for (int e = 0; e < 8; ++e) {
            float mk = (e < 4) ? m0[e] : m1[e - 4];
            float s  = s_i + ((e < 4) ? sj0[e] : sj1[e - 4]) + l1b;
            s = (s >= 0.f) ? s : SLOPE * s;
            s = (mk == 0.f) ? NEG_FILL : s;
            sc[e] = s;
            mx = fmaxf(mx, s);
        }
        #pragma unroll
        for (int off = 32; off; off >>= 1) mx = fmaxf(mx, __shfl_xor(mx, off));
        float sum = 0.f;
        #pragma unroll
        for (int e = 0; e < 8; ++e) { sc[e] = __expf(sc[e] - mx); sum += sc[e]; }
        #pragma unroll
        for (int off = 32; off; off >>= 1) sum += __shfl_xor(sum, off);
        float inv = 1.f / sum;
        f32x4 o0, o1;
        bf16x8 pk;
        #pragma unroll
        for (int e = 0; e < 4; ++e) {
            o0[e] = sc[e] * inv; o1[e] = sc[e + 4] * inv;
            pk[e]     = (short)f2bf(o0[e]);
            pk[e + 4] = (short)f2bf(o1[e]);
        }
        *(f32x4*)&a4out[(size_t)row * VV + lane * 8]     = o0;
        *(f32x4*)&a4out[(size_t)row * VV + lane * 8 + 4] = o1;
        *(bf16x8*)&tile[il][lane * 8] = pk;
    }
    __syncthreads();

    // transposed write-out: a4t[n][w][i0..i0+31]
    int i4    = (threadIdx.x & 7) * 4;
    int wbase = threadIdx.x >> 3;         // 0..31
    unsigned short* dst = a4t + (size_t)n * VV * VV + i0;
    #pragma unroll
    for (int ws = 0; ws < 16; ++ws) {
        int w = ws * 32 + wbase;
        ushort4 val;
        val.x = tile[i4 + 0][w];
        val.y = tile[i4 + 1][w];
        val.z = tile[i4 + 2][w];
        val.w = tile[i4 + 3][w];
        *(ushort4*)&dst[(size_t)w * VV + i4] = val;
    }
}

// ---------------- k3: out[n,r,w] = sum_v xc[n,r,v] * a4t[n,w,v]   (MFMA bf16)
__global__ __launch_bounds__(256) void k3_gemm(const unsigned short* __restrict__ xcb,
                                               const unsigned short* __restrict__ a4t,
                                               float* __restrict__ outp) {
    __shared__ __align__(16) unsigned short As[2][128 * 32];   // 2 x 8 KB
    __shared__ __align__(16) unsigned short Bs[2][128 * 32];   // 2 x 8 KB

    int bid = blockIdx.x;                 // n*12 + rt*4 + wt
    int n = bid / 12; int s = bid % 12; int rt = s >> 2, wt_ = s & 3;
    int r0 = rt * 128, w0 = wt_ * 128;
    int tid = threadIdx.x; int wv = tid >> 6, ln = tid & 63;
    int wr = wv >> 1, wc = wv & 1;
    const unsigned short* Ag = xcb + (size_t)n * (COUTC * TT) * VV;
    const unsigned short* Bg = a4t + (size_t)n * VV * VV;

    int fr  = ln & 15;
    int fkq = ln >> 4;
    int a_rl = ln >> 2;        // row within 16-row staging call
    int a_q  = ln & 3;         // 8-elem quarter slot

    f32x4 acc[4][4] = {};

#define STAGE(bsel, kt) do {                                                           \
        int k0_ = (kt) * 32;                                                           \
        _Pragma("unroll")                                                              \
        for (int c2 = 0; c2 < 2; ++c2) {                                               \
            int rowbase = wv * 32 + c2 * 16;                                           \
            int row_l = rowbase + a_rl;                                                \
            int sw = ((a_q ^ ((row_l >> 1) & 3)) << 3);                                \
            GLD16(Ag + (size_t)(r0 + row_l) * VV + k0_ + sw, &As[bsel][rowbase * 32]); \
            GLD16(Bg + (size_t)(w0 + row_l) * VV + k0_ + sw, &Bs[bsel][rowbase * 32]); \
        }                                                                              \
    } while (0)

    STAGE(0, 0);
    __syncthreads();

    for (int kt = 0; kt < 16; ++kt) {
        int cur = kt & 1;
        if (kt < 15) STAGE(cur ^ 1, kt + 1);   // prefetch next K-tile into other buffer

        bf16x8 af[4], bfv[4];
        #pragma unroll
        for (int mi = 0; mi < 4; ++mi) {
            int r = wr * 64 + mi * 16 + fr;
            af[mi] = *(const bf16x8*)&As[cur][r * 32 + ((fkq ^ ((r >> 1) & 3)) << 3)];
        }
        #pragma unroll
        for (int ni = 0; ni < 4; ++ni) {
            int w = wc * 64 + ni * 16 + fr;
            bfv[ni] = *(const bf16x8*)&Bs[cur][w * 32 + ((fkq ^ ((w >> 1) & 3)) << 3)];
        }
        #pragma unroll
        for (int ni = 0; ni < 4; ++ni)
            #pragma unroll
            for (int mi = 0; mi < 4; ++mi)
                acc[mi][ni] = __builtin_amdgcn_mfma_f32_16x16x32_bf16(af[mi], bfv[ni], acc[mi][ni], 0, 0, 0);

        __syncthreads();
    }
#undef STAGE

    float* og = outp + (size_t)n * (COUTC * TT) * VV;
    #pragma unroll
    for (int mi = 0; mi < 4; ++mi) {
        int rbase = r0 + wr * 64 + mi * 16 + (ln >> 4) * 4;
        #pragma unroll
        for (int ni = 0; ni < 4; ++ni) {
            int col = w0 + wc * 64 + ni * 16 + (ln & 15);
            #pragma unroll
            for (int q = 0; q < 4; ++q)
                og[(size_t)(rbase + q) * VV + col] = acc[mi][ni][q];
        }
    }
}

extern "C" void kernel_launch(void* const* d_in, const int* in_sizes, int n_in,
                              void* d_out, int out_size, void* d_ws, size_t ws_size,
                              hipStream_t stream) {
    const float* x      = (const float*)d_in[0];
    const float* A      = (const float*)d_in[1];
    const float* conv_w = (const float*)d_in[2];
    const float* conv_b = (const float*)d_in[3];
    const float* l1w    = (const float*)d_in[4];
    const float* l1b    = (const float*)d_in[5];
    const float* l2w    = (const float*)d_in[6];
    const float* l2b    = (const float*)d_in[7];

    float* outp  = (float*)d_out;                          // (N,COUT,T,V)
    float* a4out = outp + (size_t)BN * COUTC * TT * VV;    // (N,1,V,V)

    unsigned short* xcb = (unsigned short*)d_ws;                         // bf16 xc
    unsigned short* a4t = xcb + (size_t)BN * COUTC * TT * VV;            // bf16 a4^T [n][w][i]
    float* si = (float*)(a4t + (size_t)BN * VV * VV);
    float* sj = si + BN * VV;

    k0_init    <<<2 * BN * VV / 256, 256, 0, stream>>>(l1w, l2b, si);
    k1_conv    <<<BN * TT * 4, 256, 0, stream>>>(x, conv_w, conv_b, l1w, l2w, xcb, si, sj);
    k2_softmax <<<BN * 16, 256, 0, stream>>>(A, si, sj, l1b, a4out, a4t);
    k3_gemm    <<<BN * 12, 256, 0, stream>>>(xcb, a4t, outp);
}

// Round 6
// 53.718 us; speedup vs baseline: 1.4035x; 1.2225x over previous
//
#include <hip/hip_runtime.h>
#include <hip/hip_bf16.h>
#include <stdint.h>

#define BN 32
#define CIN 64
#define COUTC 64
#define TT 6
#define VV 512
#define NEG_FILL -1000.0f
#define SLOPE 0.2f

using bf16x8 = __attribute__((ext_vector_type(8))) short;
using bf16x4 = __attribute__((ext_vector_type(4))) short;
using f32x4  = __attribute__((ext_vector_type(4))) float;

static __device__ __forceinline__ unsigned short f2bf(float f) {
    union { float f; unsigned int i; } x; x.f = f;
    unsigned int r = x.i + 0x7FFFu + ((x.i >> 16) & 1u);
    return (unsigned short)(r >> 16);
}

#define GLD16(gp, lp) __builtin_amdgcn_global_load_lds( \
    (const __attribute__((address_space(1))) void*)(gp), \
    (__attribute__((address_space(3))) void*)(lp), 16, 0, 0)

// ---------------- k1: xc = W·x + b via MFMA (bf16 inputs, f32 accum)
//   block = (n, t, vq): M=64 (o) x N=128 (v) x K=64 (i)
//   + fused spart epilogue: spartS/D[n][t][v] = l2w[t] * sum_o w_src/dst[o] * z[o][v]
__global__ __launch_bounds__(256) void k1_conv(const float* __restrict__ x,
                                               const float* __restrict__ W,
                                               const float* __restrict__ bias,
                                               const float* __restrict__ l1w,
                                               const float* __restrict__ l2w,
                                               unsigned short* __restrict__ xcb,
                                               float* __restrict__ spartS,
                                               float* __restrict__ spartD) {
    __shared__ __align__(16) unsigned short Ws[64 * 64];    // 8 KB  [o][i] octet-swizzled
    __shared__ __align__(16) unsigned short Bs[128 * 64];   // 16 KB [v][i] octet-swizzled; reused for out
    int bid = blockIdx.x;                  // (n*T + t)*4 + vq
    int vq = bid & 3; int nt = bid >> 2; int t = nt % TT; int n = nt / TT;
    int tid = threadIdx.x; int wv = tid >> 6, ln = tid & 63;
    int v0 = vq * 128;

    // --- stage W (f32 -> bf16, swizzled): thread handles o=tid>>2, i16=(tid&3)*16
    {
        int o = tid >> 2, i16 = (tid & 3) * 16;
        const float* wr_ = W + o * CIN + i16;
        f32x4 a = *(const f32x4*)&wr_[0], b = *(const f32x4*)&wr_[4];
        f32x4 c = *(const f32x4*)&wr_[8], d = *(const f32x4*)&wr_[12];
        bf16x8 p0, p1;
        #pragma unroll
        for (int e = 0; e < 4; ++e) {
            p0[e] = (short)f2bf(a[e]); p0[e + 4] = (short)f2bf(b[e]);
            p1[e] = (short)f2bf(c[e]); p1[e + 4] = (short)f2bf(d[e]);
        }
        int j0 = i16 >> 3;    // octet index (0..7)
        *(bf16x8*)&Ws[o * 64 + ((j0 ^ (o & 7)) << 3)]       = p0;
        *(bf16x8*)&Ws[o * 64 + (((j0 + 1) ^ (o & 7)) << 3)] = p1;
    }
    // --- stage x^T (f32 -> bf16, transposed into [v][i], swizzled)
    const float* xg = x + ((size_t)(n * CIN) * TT + t) * VV + v0;
    {
        int v4 = (tid & 31) * 4;
        int ig0 = tid >> 5;                // 0..7
        #pragma unroll
        for (int g = 0; g < 2; ++g) {
            int i4 = (ig0 + g * 8) * 4;    // 4-row group of i
            f32x4 r0 = *(const f32x4*)&xg[(size_t)(i4 + 0) * TT * VV + v4];
            f32x4 r1 = *(const f32x4*)&xg[(size_t)(i4 + 1) * TT * VV + v4];
            f32x4 r2 = *(const f32x4*)&xg[(size_t)(i4 + 2) * TT * VV + v4];
            f32x4 r3 = *(const f32x4*)&xg[(size_t)(i4 + 3) * TT * VV + v4];
            int j = i4 >> 3, h = (i4 >> 2) & 1;
            #pragma unroll
            for (int c = 0; c < 4; ++c) {
                int v = v4 + c;
                bf16x4 col;
                col[0] = (short)f2bf(r0[c]); col[1] = (short)f2bf(r1[c]);
                col[2] = (short)f2bf(r2[c]); col[3] = (short)f2bf(r3[c]);
                *(bf16x4*)&Bs[v * 64 + ((j ^ (v & 7)) << 3) + h * 4] = col;
            }
        }
    }
    __syncthreads();

    // --- MFMA: D[o][v], A=Ws rows o, B=Bs rows v (both [row][k] — proven k3 pattern)
    int fr = ln & 15, fkq = ln >> 4;
    f32x4 acc[4][2] = {};
    #pragma unroll
    for (int ks = 0; ks < 2; ++ks) {
        bf16x8 af[4], bfv[2];
        int oct = fkq + ks * 4;
        #pragma unroll
        for (int mi = 0; mi < 4; ++mi) {
            int o = mi * 16 + fr;
            af[mi] = *(const bf16x8*)&Ws[o * 64 + ((oct ^ (o & 7)) << 3)];
        }
        #pragma unroll
        for (int ni = 0; ni < 2; ++ni) {
            int v = wv * 32 + ni * 16 + fr;
            bfv[ni] = *(const bf16x8*)&Bs[v * 64 + ((oct ^ (v & 7)) << 3)];
        }
        #pragma unroll
        for (int mi = 0; mi < 4; ++mi)
            #pragma unroll
            for (int ni = 0; ni < 2; ++ni)
                acc[mi][ni] = __builtin_amdgcn_mfma_f32_16x16x32_bf16(af[mi], bfv[ni], acc[mi][ni], 0, 0, 0);
    }
    __syncthreads();   // all Bs fragment reads done; safe to reuse Bs for output staging

    // --- epilogue: z = acc + bias; spart partials (reduce over o); stage bf16 out
    float l2wt = l2w[t];
    float partS[2] = {0.f, 0.f}, partD[2] = {0.f, 0.f};
    #pragma unroll
    for (int mi = 0; mi < 4; ++mi)
        #pragma unroll
        for (int q = 0; q < 4; ++q) {
            int o = mi * 16 + (ln >> 4) * 4 + q;
            float bv = bias[o];
            float wS = l1w[o], wD = l1w[COUTC + o];
            #pragma unroll
            for (int ni = 0; ni < 2; ++ni) {
                float z = acc[mi][ni][q] + bv;
                partS[ni] += wS * z;
                partD[ni] += wD * z;
                int vloc = wv * 32 + ni * 16 + fr;
                int vsw = (((vloc >> 3) ^ (o & 15)) << 3) | (vloc & 7);
                Bs[o * 128 + vsw] = f2bf(z);    // out-stage [o][v], octet-swizzled
            }
        }
    // reduce over the 4 lane-groups (o-rows within frag) -> full sum per v
    #pragma unroll
    for (int ni = 0; ni < 2; ++ni) {
        float sS = partS[ni], sD = partD[ni];
        sS += __shfl_xor(sS, 16); sS += __shfl_xor(sS, 32);
        sD += __shfl_xor(sD, 16); sD += __shfl_xor(sD, 32);
        if (ln < 16) {
            int v = v0 + wv * 32 + ni * 16 + ln;
            size_t si_ = ((size_t)n * TT + t) * VV + v;
            spartS[si_] = l2wt * sS;
            spartD[si_] = l2wt * sD;
        }
    }
    __syncthreads();

    // --- coalesced write-out of xcb from LDS
    {
        int o = tid >> 2, c32 = (tid & 3) * 32;
        size_t base = ((size_t)(n * COUTC + o) * TT + t) * VV + v0 + c32;
        #pragma unroll
        for (int q = 0; q < 4; ++q) {
            int oct = (tid & 3) * 4 + q;
            bf16x8 val = *(const bf16x8*)&Bs[o * 128 + ((oct ^ (o & 15)) << 3)];
            *(bf16x8*)&xcb[base + q * 8] = val;
        }
    }
}

// ---------------- k2: softmax rows -> a4 f32 (d_out) + fused LDS transpose -> a4t bf16
//   si/sj folded from spart (6-term t-sum) + l2b/l1b constants.
__global__ __launch_bounds__(256) void k2_softmax(const float* __restrict__ A,
                                                  const float* __restrict__ spartS,
                                                  const float* __restrict__ spartD,
                                                  const float* __restrict__ l1w,
                                                  const float* __restrict__ l1b_,
                                                  const float* __restrict__ l2b_,
                                                  float* __restrict__ a4out,
                                                  unsigned short* __restrict__ a4t) {
    __shared__ unsigned short tile[32][520];   // 32 rows x 512 (+8 pad), 32.5 KB
    __shared__ float si_loc[32];
    int blk = blockIdx.x;                 // n*16 + ib
    int n = blk >> 4; int i0 = (blk & 15) * 32;
    int wv = threadIdx.x >> 6, lane = threadIdx.x & 63;

    float sws = 0.f, swd = 0.f;
    for (int c = 0; c < COUTC; ++c) { sws += l1w[c]; swd += l1w[COUTC + c]; }
    float l2b = l2b_[0], l1b = l1b_[0];

    if (threadIdx.x < 32) {
        float s = 0.f;
        #pragma unroll
        for (int t = 0; t < TT; ++t)
            s += spartS[((size_t)n * TT + t) * VV + i0 + threadIdx.x];
        si_loc[threadIdx.x] = s + l2b * sws;
    }
    f32x4 sj0 = {0.f, 0.f, 0.f, 0.f}, sj1 = {0.f, 0.f, 0.f, 0.f};
    #pragma unroll
    for (int t = 0; t < TT; ++t) {
        const float* p = &spartD[((size_t)n * TT + t) * VV + lane * 8];
        f32x4 d0 = *(const f32x4*)&p[0];
        f32x4 d1 = *(const f32x4*)&p[4];
        #pragma unroll
        for (int e = 0; e < 4; ++e) { sj0[e] += d0[e]; sj1[e] += d1[e]; }
    }
    float cst = l2b * swd + l1b;
    #pragma unroll
    for (int e = 0; e < 4; ++e) { sj0[e] += cst; sj1[e] += cst; }
    __syncthreads();

    for (int it = 0; it < 8; ++it) {
        int il = it * 4 + wv;             // local row 0..31
        int i  = i0 + il;
        int row = n * VV + i;
        float s_i = si_loc[il];
        const float* mrow = A + ((size_t)n * 8 + 7) * VV * VV + (size_t)i * VV;
        f32x4 m0 = *(const f32x4*)&mrow[lane * 8];
        f32x4 m1 = *(const f32x4*)&mrow[lane * 8 + 4];

        float sc[8];
        float mx = -1e30f;
        #pragma unroll
        for (int e = 0; e < 8; ++e) {
            float mk = (e < 4) ? m0[e] : m1[e - 4];
            float s  = s_i + ((e < 4) ? sj0[e] : sj1[e - 4]);
            s = (s >= 0.f) ? s : SLOPE * s;
            s = (mk == 0.f) ? NEG_FILL : s;
            sc[e] = s;
            mx = fmaxf(mx, s);
        }
        #pragma unroll
        for (int off = 32; off; off >>= 1) mx = fmaxf(mx, __shfl_xor(mx, off));
        float sum = 0.f;
        #pragma unroll
        for (int e = 0; e < 8; ++e) { sc[e] = __expf(sc[e] - mx); sum += sc[e]; }
        #pragma unroll
        for (int off = 32; off; off >>= 1) sum += __shfl_xor(sum, off);
        float inv = 1.f / sum;
        f32x4 o0, o1;
        bf16x8 pk;
        #pragma unroll
        for (int e = 0; e < 4; ++e) {
            o0[e] = sc[e] * inv; o1[e] = sc[e + 4] * inv;
            pk[e]     = (short)f2bf(o0[e]);
            pk[e + 4] = (short)f2bf(o1[e]);
        }
        *(f32x4*)&a4out[(size_t)row * VV + lane * 8]     = o0;
        *(f32x4*)&a4out[(size_t)row * VV + lane * 8 + 4] = o1;
        *(bf16x8*)&tile[il][lane * 8] = pk;
    }
    __syncthreads();

    // transposed write-out: a4t[n][w][i0..i0+31]
    int i4    = (threadIdx.x & 7) * 4;
    int wbase = threadIdx.x >> 3;         // 0..31
    unsigned short* dst = a4t + (size_t)n * VV * VV + i0;
    #pragma unroll
    for (int ws = 0; ws < 16; ++ws) {
        int w = ws * 32 + wbase;
        ushort4 val;
        val.x = tile[i4 + 0][w];
        val.y = tile[i4 + 1][w];
        val.z = tile[i4 + 2][w];
        val.w = tile[i4 + 3][w];
        *(ushort4*)&dst[(size_t)w * VV + i4] = val;
    }
}

// ---------------- k3: out[n,r,w] = sum_v xc[n,r,v] * a4t[n,w,v]   (MFMA bf16)
//   512 threads / 8 waves (2 r x 4 w), double-buffered, quarter-XOR swizzle.
__global__ __launch_bounds__(512) void k3_gemm(const unsigned short* __restrict__ xcb,
                                               const unsigned short* __restrict__ a4t,
                                               float* __restrict__ outp) {
    __shared__ __align__(16) unsigned short As[2][128 * 32];   // 2 x 8 KB
    __shared__ __align__(16) unsigned short Bs[2][128 * 32];   // 2 x 8 KB

    int bid = blockIdx.x;                 // n*12 + rt*4 + wt
    int n = bid / 12; int s = bid % 12; int rt = s >> 2, wt_ = s & 3;
    int r0 = rt * 128, w0 = wt_ * 128;
    int tid = threadIdx.x; int wv = tid >> 6, ln = tid & 63;
    int wr = wv >> 2, wc = wv & 3;
    const unsigned short* Ag = xcb + (size_t)n * (COUTC * TT) * VV;
    const unsigned short* Bg = a4t + (size_t)n * VV * VV;

    int fr  = ln & 15;
    int fkq = ln >> 4;
    int row_l = tid >> 2;                 // 0..127 (one GLD16 covers the full tile)
    int sw_st = (((tid & 3) ^ ((row_l >> 1) & 3)) << 3);

    f32x4 acc[4][2] = {};

#define STAGE(bsel, kt) do {                                                        \
        int k0_ = (kt) * 32;                                                        \
        GLD16(Ag + (size_t)(r0 + row_l) * VV + k0_ + sw_st,                         \
              &As[bsel][(wv * 16) * 32]);                                           \
        GLD16(Bg + (size_t)(w0 + row_l) * VV + k0_ + sw_st,                         \
              &Bs[bsel][(wv * 16) * 32]);                                           \
    } while (0)

    STAGE(0, 0);
    __syncthreads();

    for (int kt = 0; kt < 16; ++kt) {
        int cur = kt & 1;
        if (kt < 15) STAGE(cur ^ 1, kt + 1);   // prefetch next K-tile into other buffer

        bf16x8 af[4], bfv[2];
        #pragma unroll
        for (int mi = 0; mi < 4; ++mi) {
            int r = wr * 64 + mi * 16 + fr;
            af[mi] = *(const bf16x8*)&As[cur][r * 32 + ((fkq ^ ((r >> 1) & 3)) << 3)];
        }
        #pragma unroll
        for (int ni = 0; ni < 2; ++ni) {
            int w = wc * 32 + ni * 16 + fr;
            bfv[ni] = *(const bf16x8*)&Bs[cur][w * 32 + ((fkq ^ ((w >> 1) & 3)) << 3)];
        }
        #pragma unroll
        for (int ni = 0; ni < 2; ++ni)
            #pragma unroll
            for (int mi = 0; mi < 4; ++mi)
                acc[mi][ni] = __builtin_amdgcn_mfma_f32_16x16x32_bf16(af[mi], bfv[ni], acc[mi][ni], 0, 0, 0);

        __syncthreads();
    }
#undef STAGE

    float* og = outp + (size_t)n * (COUTC * TT) * VV;
    #pragma unroll
    for (int mi = 0; mi < 4; ++mi) {
        int rbase = r0 + wr * 64 + mi * 16 + (ln >> 4) * 4;
        #pragma unroll
        for (int ni = 0; ni < 2; ++ni) {
            int col = w0 + wc * 32 + ni * 16 + (ln & 15);
            #pragma unroll
            for (int q = 0; q < 4; ++q)
                og[(size_t)(rbase + q) * VV + col] = acc[mi][ni][q];
        }
    }
}

extern "C" void kernel_launch(void* const* d_in, const int* in_sizes, int n_in,
                              void* d_out, int out_size, void* d_ws, size_t ws_size,
                              hipStream_t stream) {
    const float* x      = (const float*)d_in[0];
    const float* A      = (const float*)d_in[1];
    const float* conv_w = (const float*)d_in[2];
    const float* conv_b = (const float*)d_in[3];
    const float* l1w    = (const float*)d_in[4];
    const float* l1b    = (const float*)d_in[5];
    const float* l2w    = (const float*)d_in[6];
    const float* l2b    = (const float*)d_in[7];

    float* outp  = (float*)d_out;                          // (N,COUT,T,V)
    float* a4out = outp + (size_t)BN * COUTC * TT * VV;    // (N,1,V,V)

    unsigned short* xcb = (unsigned short*)d_ws;                         // bf16 xc
    unsigned short* a4t = xcb + (size_t)BN * COUTC * TT * VV;            // bf16 a4^T [n][w][i]
    float* spartS = (float*)(a4t + (size_t)BN * VV * VV);                // [n][t][v]
    float* spartD = spartS + (size_t)BN * TT * VV;

    k1_conv    <<<BN * TT * 4, 256, 0, stream>>>(x, conv_w, conv_b, l1w, l2w, xcb, spartS, spartD);
    k2_softmax <<<BN * 16, 256, 0, stream>>>(A, spartS, spartD, l1w, l1b, l2b, a4out, a4t);
    k3_gemm    <<<BN * 12, 512, 0, stream>>>(xcb, a4t, outp);
}

// Round 7
// 47.572 us; speedup vs baseline: 1.5848x; 1.1292x over previous
//
#include <hip/hip_runtime.h>
#include <hip/hip_bf16.h>
#include <stdint.h>

#define BN 32
#define CIN 64
#define COUTC 64
#define TT 6
#define VV 512
#define NEG_FILL -1000.0f
#define SLOPE 0.2f

using bf16x8 = __attribute__((ext_vector_type(8))) short;
using bf16x4 = __attribute__((ext_vector_type(4))) short;
using f32x4  = __attribute__((ext_vector_type(4))) float;

static __device__ __forceinline__ unsigned short f2bf(float f) {
    union { float f; unsigned int i; } x; x.f = f;
    unsigned int r = x.i + 0x7FFFu + ((x.i >> 16) & 1u);
    return (unsigned short)(r >> 16);
}

#define GLD16(gp, lp) __builtin_amdgcn_global_load_lds( \
    (const __attribute__((address_space(1))) void*)(gp), \
    (__attribute__((address_space(3))) void*)(lp), 16, 0, 0)

// ---------------- k1: xc = W·x + b via MFMA (bf16 inputs, f32 accum)
//   (unchanged from round 6 — proven)
__global__ __launch_bounds__(256) void k1_conv(const float* __restrict__ x,
                                               const float* __restrict__ W,
                                               const float* __restrict__ bias,
                                               const float* __restrict__ l1w,
                                               const float* __restrict__ l2w,
                                               unsigned short* __restrict__ xcb,
                                               float* __restrict__ spartS,
                                               float* __restrict__ spartD) {
    __shared__ __align__(16) unsigned short Ws[64 * 64];    // 8 KB  [o][i] octet-swizzled
    __shared__ __align__(16) unsigned short Bs[128 * 64];   // 16 KB [v][i]; reused for out
    int bid = blockIdx.x;                  // (n*T + t)*4 + vq
    int vq = bid & 3; int nt = bid >> 2; int t = nt % TT; int n = nt / TT;
    int tid = threadIdx.x; int wv = tid >> 6, ln = tid & 63;
    int v0 = vq * 128;

    {
        int o = tid >> 2, i16 = (tid & 3) * 16;
        const float* wr_ = W + o * CIN + i16;
        f32x4 a = *(const f32x4*)&wr_[0], b = *(const f32x4*)&wr_[4];
        f32x4 c = *(const f32x4*)&wr_[8], d = *(const f32x4*)&wr_[12];
        bf16x8 p0, p1;
        #pragma unroll
        for (int e = 0; e < 4; ++e) {
            p0[e] = (short)f2bf(a[e]); p0[e + 4] = (short)f2bf(b[e]);
            p1[e] = (short)f2bf(c[e]); p1[e + 4] = (short)f2bf(d[e]);
        }
        int j0 = i16 >> 3;
        *(bf16x8*)&Ws[o * 64 + ((j0 ^ (o & 7)) << 3)]       = p0;
        *(bf16x8*)&Ws[o * 64 + (((j0 + 1) ^ (o & 7)) << 3)] = p1;
    }
    const float* xg = x + ((size_t)(n * CIN) * TT + t) * VV + v0;
    {
        int v4 = (tid & 31) * 4;
        int ig0 = tid >> 5;
        #pragma unroll
        for (int g = 0; g < 2; ++g) {
            int i4 = (ig0 + g * 8) * 4;
            f32x4 r0 = *(const f32x4*)&xg[(size_t)(i4 + 0) * TT * VV + v4];
            f32x4 r1 = *(const f32x4*)&xg[(size_t)(i4 + 1) * TT * VV + v4];
            f32x4 r2 = *(const f32x4*)&xg[(size_t)(i4 + 2) * TT * VV + v4];
            f32x4 r3 = *(const f32x4*)&xg[(size_t)(i4 + 3) * TT * VV + v4];
            int j = i4 >> 3, h = (i4 >> 2) & 1;
            #pragma unroll
            for (int c = 0; c < 4; ++c) {
                int v = v4 + c;
                bf16x4 col;
                col[0] = (short)f2bf(r0[c]); col[1] = (short)f2bf(r1[c]);
                col[2] = (short)f2bf(r2[c]); col[3] = (short)f2bf(r3[c]);
                *(bf16x4*)&Bs[v * 64 + ((j ^ (v & 7)) << 3) + h * 4] = col;
            }
        }
    }
    __syncthreads();

    int fr = ln & 15, fkq = ln >> 4;
    f32x4 acc[4][2] = {};
    #pragma unroll
    for (int ks = 0; ks < 2; ++ks) {
        bf16x8 af[4], bfv[2];
        int oct = fkq + ks * 4;
        #pragma unroll
        for (int mi = 0; mi < 4; ++mi) {
            int o = mi * 16 + fr;
            af[mi] = *(const bf16x8*)&Ws[o * 64 + ((oct ^ (o & 7)) << 3)];
        }
        #pragma unroll
        for (int ni = 0; ni < 2; ++ni) {
            int v = wv * 32 + ni * 16 + fr;
            bfv[ni] = *(const bf16x8*)&Bs[v * 64 + ((oct ^ (v & 7)) << 3)];
        }
        #pragma unroll
        for (int mi = 0; mi < 4; ++mi)
            #pragma unroll
            for (int ni = 0; ni < 2; ++ni)
                acc[mi][ni] = __builtin_amdgcn_mfma_f32_16x16x32_bf16(af[mi], bfv[ni], acc[mi][ni], 0, 0, 0);
    }
    __syncthreads();

    float l2wt = l2w[t];
    float partS[2] = {0.f, 0.f}, partD[2] = {0.f, 0.f};
    #pragma unroll
    for (int mi = 0; mi < 4; ++mi)
        #pragma unroll
        for (int q = 0; q < 4; ++q) {
            int o = mi * 16 + (ln >> 4) * 4 + q;
            float bv = bias[o];
            float wS = l1w[o], wD = l1w[COUTC + o];
            #pragma unroll
            for (int ni = 0; ni < 2; ++ni) {
                float z = acc[mi][ni][q] + bv;
                partS[ni] += wS * z;
                partD[ni] += wD * z;
                int vloc = wv * 32 + ni * 16 + fr;
                int vsw = (((vloc >> 3) ^ (o & 15)) << 3) | (vloc & 7);
                Bs[o * 128 + vsw] = f2bf(z);
            }
        }
    #pragma unroll
    for (int ni = 0; ni < 2; ++ni) {
        float sS = partS[ni], sD = partD[ni];
        sS += __shfl_xor(sS, 16); sS += __shfl_xor(sS, 32);
        sD += __shfl_xor(sD, 16); sD += __shfl_xor(sD, 32);
        if (ln < 16) {
            int v = v0 + wv * 32 + ni * 16 + ln;
            size_t si_ = ((size_t)n * TT + t) * VV + v;
            spartS[si_] = l2wt * sS;
            spartD[si_] = l2wt * sD;
        }
    }
    __syncthreads();

    {
        int o = tid >> 2, c32 = (tid & 3) * 32;
        size_t base = ((size_t)(n * COUTC + o) * TT + t) * VV + v0 + c32;
        #pragma unroll
        for (int q = 0; q < 4; ++q) {
            int oct = (tid & 3) * 4 + q;
            bf16x8 val = *(const bf16x8*)&Bs[o * 128 + ((oct ^ (o & 15)) << 3)];
            *(bf16x8*)&xcb[base + q * 8] = val;
        }
    }
}

// ---------------- k2: softmax rows -> a4 f32 (d_out) + fused LDS transpose -> a4t bf16
//   512 threads / 8 waves (4 rows per wave): 16 waves/CU for latency hiding.
__global__ __launch_bounds__(512) void k2_softmax(const float* __restrict__ A,
                                                  const float* __restrict__ spartS,
                                                  const float* __restrict__ spartD,
                                                  const float* __restrict__ l1w,
                                                  const float* __restrict__ l1b_,
                                                  const float* __restrict__ l2b_,
                                                  float* __restrict__ a4out,
                                                  unsigned short* __restrict__ a4t) {
    __shared__ unsigned short tile[32][520];   // 32 rows x 512 (+8 pad), 32.5 KB
    __shared__ float si_loc[32];
    int blk = blockIdx.x;                 // n*16 + ib
    int n = blk >> 4; int i0 = (blk & 15) * 32;
    int wv = threadIdx.x >> 6, lane = threadIdx.x & 63;

    float sws = 0.f, swd = 0.f;
    for (int c = 0; c < COUTC; ++c) { sws += l1w[c]; swd += l1w[COUTC + c]; }
    float l2b = l2b_[0], l1b = l1b_[0];

    if (threadIdx.x < 32) {
        float s = 0.f;
        #pragma unroll
        for (int t = 0; t < TT; ++t)
            s += spartS[((size_t)n * TT + t) * VV + i0 + threadIdx.x];
        si_loc[threadIdx.x] = s + l2b * sws;
    }
    f32x4 sj0 = {0.f, 0.f, 0.f, 0.f}, sj1 = {0.f, 0.f, 0.f, 0.f};
    #pragma unroll
    for (int t = 0; t < TT; ++t) {
        const float* p = &spartD[((size_t)n * TT + t) * VV + lane * 8];
        f32x4 d0 = *(const f32x4*)&p[0];
        f32x4 d1 = *(const f32x4*)&p[4];
        #pragma unroll
        for (int e = 0; e < 4; ++e) { sj0[e] += d0[e]; sj1[e] += d1[e]; }
    }
    float cst = l2b * swd + l1b;
    #pragma unroll
    for (int e = 0; e < 4; ++e) { sj0[e] += cst; sj1[e] += cst; }
    __syncthreads();

    for (int it = 0; it < 4; ++it) {
        int il = it * 8 + wv;             // local row 0..31
        int i  = i0 + il;
        int row = n * VV + i;
        float s_i = si_loc[il];
        const float* mrow = A + ((size_t)n * 8 + 7) * VV * VV + (size_t)i * VV;
        f32x4 m0 = *(const f32x4*)&mrow[lane * 8];
        f32x4 m1 = *(const f32x4*)&mrow[lane * 8 + 4];

        float sc[8];
        float mx = -1e30f;
        #pragma unroll
        for (int e = 0; e < 8; ++e) {
            float mk = (e < 4) ? m0[e] : m1[e - 4];
            float s  = s_i + ((e < 4) ? sj0[e] : sj1[e - 4]);
            s = (s >= 0.f) ? s : SLOPE * s;
            s = (mk == 0.f) ? NEG_FILL : s;
            sc[e] = s;
            mx = fmaxf(mx, s);
        }
        #pragma unroll
        for (int off = 32; off; off >>= 1) mx = fmaxf(mx, __shfl_xor(mx, off));
        float sum = 0.f;
        #pragma unroll
        for (int e = 0; e < 8; ++e) { sc[e] = __expf(sc[e] - mx); sum += sc[e]; }
        #pragma unroll
        for (int off = 32; off; off >>= 1) sum += __shfl_xor(sum, off);
        float inv = 1.f / sum;
        f32x4 o0, o1;
        bf16x8 pk;
        #pragma unroll
        for (int e = 0; e < 4; ++e) {
            o0[e] = sc[e] * inv; o1[e] = sc[e + 4] * inv;
            pk[e]     = (short)f2bf(o0[e]);
            pk[e + 4] = (short)f2bf(o1[e]);
        }
        *(f32x4*)&a4out[(size_t)row * VV + lane * 8]     = o0;
        *(f32x4*)&a4out[(size_t)row * VV + lane * 8 + 4] = o1;
        *(bf16x8*)&tile[il][lane * 8] = pk;
    }
    __syncthreads();

    // transposed write-out: a4t[n][w][i0..i0+31], 64 w-rows per pass, 8 passes
    int i4    = (threadIdx.x & 7) * 4;
    int wbase = threadIdx.x >> 3;         // 0..63
    unsigned short* dst = a4t + (size_t)n * VV * VV + i0;
    #pragma unroll
    for (int ws = 0; ws < 8; ++ws) {
        int w = ws * 64 + wbase;
        ushort4 val;
        val.x = tile[i4 + 0][w];
        val.y = tile[i4 + 1][w];
        val.z = tile[i4 + 2][w];
        val.w = tile[i4 + 3][w];
        *(ushort4*)&dst[(size_t)w * VV + i4] = val;
    }
}

// ---------------- k3: out[n,r,w] = sum_v xc[n,r,v] * a4t[n,w,v]   (MFMA bf16)
//   768 blocks x 256 threads (exactly 3 blocks/CU), tile M=64 N=128 BK=64,
//   double-buffered (8 K-steps), octet-XOR swizzle, XCD-aware block swizzle.
__global__ __launch_bounds__(256) void k3_gemm(const unsigned short* __restrict__ xcb,
                                               const unsigned short* __restrict__ a4t,
                                               float* __restrict__ outp) {
    __shared__ __align__(16) unsigned short As[2][64 * 64];    // 2 x 8 KB
    __shared__ __align__(16) unsigned short Bs[2][128 * 64];   // 2 x 16 KB

    // XCD-aware swizzle: 768 = 8 x 96, bijective; groups same-n blocks per XCD
    int bid = (blockIdx.x & 7) * 96 + (blockIdx.x >> 3);
    int n = bid / 24; int s = bid % 24; int rt = s >> 2, wt_ = s & 3;
    int r0 = rt * 64, w0 = wt_ * 128;
    int tid = threadIdx.x; int wv = tid >> 6, ln = tid & 63;
    int wr = wv >> 1, wc = wv & 1;        // wave tile: r in [wr*32,+32), w in [wc*64,+64)
    const unsigned short* Ag = xcb + (size_t)n * (COUTC * TT) * VV;
    const unsigned short* Bg = a4t + (size_t)n * VV * VV;

    int fr  = ln & 15;
    int fkq = ln >> 4;
    int st_row = tid >> 3;                // 0..31
    int st_g   = tid & 7;                 // 16B granule 0..7

    f32x4 acc[2][4] = {};

#define STAGE(bsel, kt) do {                                                          \
        int k0_ = (kt) * 64;                                                          \
        _Pragma("unroll")                                                             \
        for (int c2 = 0; c2 < 2; ++c2) {                                              \
            int row = c2 * 32 + st_row;                                               \
            GLD16(Ag + (size_t)(r0 + row) * VV + k0_ + ((st_g ^ (row & 7)) << 3),     \
                  &As[bsel][c2 * 2048 + wv * 512]);                                   \
        }                                                                             \
        _Pragma("unroll")                                                             \
        for (int c4 = 0; c4 < 4; ++c4) {                                              \
            int row = c4 * 32 + st_row;                                               \
            GLD16(Bg + (size_t)(w0 + row) * VV + k0_ + ((st_g ^ (row & 7)) << 3),     \
                  &Bs[bsel][c4 * 2048 + wv * 512]);                                   \
        }                                                                             \
    } while (0)

    STAGE(0, 0);
    __syncthreads();

    for (int kt = 0; kt < 8; ++kt) {
        int cur = kt & 1;
        if (kt < 7) STAGE(cur ^ 1, kt + 1);   // prefetch next K-tile into other buffer

        #pragma unroll
        for (int ks = 0; ks < 2; ++ks) {
            int g = ks * 4 + fkq;
            bf16x8 af[2], bfv[4];
            #pragma unroll
            for (int mi = 0; mi < 2; ++mi) {
                int r = wr * 32 + mi * 16 + fr;
                af[mi] = *(const bf16x8*)&As[cur][r * 64 + ((g ^ (r & 7)) << 3)];
            }
            #pragma unroll
            for (int ni = 0; ni < 4; ++ni) {
                int w = wc * 64 + ni * 16 + fr;
                bfv[ni] = *(const bf16x8*)&Bs[cur][w * 64 + ((g ^ (w & 7)) << 3)];
            }
            #pragma unroll
            for (int ni = 0; ni < 4; ++ni)
                #pragma unroll
                for (int mi = 0; mi < 2; ++mi)
                    acc[mi][ni] = __builtin_amdgcn_mfma_f32_16x16x32_bf16(af[mi], bfv[ni], acc[mi][ni], 0, 0, 0);
        }
        __syncthreads();
    }
#undef STAGE

    float* og = outp + (size_t)n * (COUTC * TT) * VV;
    #pragma unroll
    for (int mi = 0; mi < 2; ++mi) {
        int rbase = r0 + wr * 32 + mi * 16 + (ln >> 4) * 4;
        #pragma unroll
        for (int ni = 0; ni < 4; ++ni) {
            int col = w0 + wc * 64 + ni * 16 + (ln & 15);
            #pragma unroll
            for (int q = 0; q < 4; ++q)
                og[(size_t)(rbase + q) * VV + col] = acc[mi][ni][q];
        }
    }
}

extern "C" void kernel_launch(void* const* d_in, const int* in_sizes, int n_in,
                              void* d_out, int out_size, void* d_ws, size_t ws_size,
                              hipStream_t stream) {
    const float* x      = (const float*)d_in[0];
    const float* A      = (const float*)d_in[1];
    const float* conv_w = (const float*)d_in[2];
    const float* conv_b = (const float*)d_in[3];
    const float* l1w    = (const float*)d_in[4];
    const float* l1b    = (const float*)d_in[5];
    const float* l2w    = (const float*)d_in[6];
    const float* l2b    = (const float*)d_in[7];

    float* outp  = (float*)d_out;                          // (N,COUT,T,V)
    float* a4out = outp + (size_t)BN * COUTC * TT * VV;    // (N,1,V,V)

    unsigned short* xcb = (unsigned short*)d_ws;                         // bf16 xc
    unsigned short* a4t = xcb + (size_t)BN * COUTC * TT * VV;            // bf16 a4^T [n][w][i]
    float* spartS = (float*)(a4t + (size_t)BN * VV * VV);                // [n][t][v]
    float* spartD = spartS + (size_t)BN * TT * VV;

    k1_conv    <<<BN * TT * 4, 256, 0, stream>>>(x, conv_w, conv_b, l1w, l2w, xcb, spartS, spartD);
    k2_softmax <<<BN * 16, 512, 0, stream>>>(A, spartS, spartD, l1w, l1b, l2b, a4out, a4t);
    k3_gemm    <<<BN * 24, 256, 0, stream>>>(xcb, a4t, outp);
}